// Round 3
// baseline (273.364 us; speedup 1.0000x reference)
//
#include <hip/hip_runtime.h>
#include <hip/hip_bf16.h>
#include <math.h>

#define N_TOK 8192
#define DIM   1024
#define NEXP  16
#define TOPK  2
#define CAPE  1024
#define NSLOT (N_TOK*TOPK)

typedef __attribute__((ext_vector_type(8))) short     short8;
typedef __attribute__((ext_vector_type(4))) float     floatx4;
typedef __attribute__((ext_vector_type(4))) unsigned short ushort4v;

__device__ __forceinline__ unsigned short f2bf(float f) {
    unsigned u = __float_as_uint(f);
    u += 0x7FFFu + ((u >> 16) & 1u);   // round-to-nearest-even
    return (unsigned short)(u >> 16);
}

// async global->LDS, 16B per lane; LDS dest = wave-uniform base + lane*16
#define GLOAD_LDS16(g, l) __builtin_amdgcn_global_load_lds( \
    (const __attribute__((address_space(1))) unsigned int*)(g), \
    (__attribute__((address_space(3))) unsigned int*)(l), 16, 0, 0)

#define RAW_BARRIER() asm volatile("s_barrier" ::: "memory")

// ---------------- gw transpose: [D,E] -> [E,D] (64 KB, one-shot) -----------
__global__ void gwt_kernel(const float* __restrict__ gw, float* __restrict__ gwT) {
    int i = blockIdx.x * 256 + threadIdx.x;
    if (i >= DIM * NEXP) return;
    int d = i >> 4, e = i & 15;
    gwT[e * DIM + d] = gw[i];
}

// ------- gate: logits -> top2 -> softmax -> slot records; fused x->bf16 ----
__global__ __launch_bounds__(256) void gate_kernel(
        const float* __restrict__ x,
        const float* __restrict__ gwT,
        const float* __restrict__ gb,
        int* __restrict__ slot_expert,
        unsigned long long* __restrict__ slot_key,
        float* __restrict__ slot_gate,
        unsigned short* __restrict__ Xb) {
    const int t    = blockIdx.x * 4 + (threadIdx.x >> 6);
    const int lane = threadIdx.x & 63;

    const floatx4* xr = (const floatx4*)(x + (size_t)t * DIM);
    ushort4v* Xb4 = (ushort4v*)Xb + (size_t)t * 256;
    floatx4 xv[4];
#pragma unroll
    for (int i = 0; i < 4; i++) {
        xv[i] = xr[lane + i * 64];
        ushort4v o;
        o[0] = f2bf(xv[i][0]); o[1] = f2bf(xv[i][1]);
        o[2] = f2bf(xv[i][2]); o[3] = f2bf(xv[i][3]);
        Xb4[lane + i * 64] = o;
    }

    float acc[NEXP];
#pragma unroll
    for (int e = 0; e < NEXP; e++) {
        const floatx4* wr = (const floatx4*)(gwT + (size_t)e * DIM);
        float a = 0.f;
#pragma unroll
        for (int i = 0; i < 4; i++) {
            floatx4 w = wr[lane + i * 64];
            a += xv[i][0]*w[0] + xv[i][1]*w[1] + xv[i][2]*w[2] + xv[i][3]*w[3];
        }
        acc[e] = a;
    }
#pragma unroll
    for (int off = 32; off > 0; off >>= 1) {
#pragma unroll
        for (int e = 0; e < NEXP; e++) acc[e] += __shfl_down(acc[e], off, 64);
    }
    if (lane == 0) {
        float v0 = -1e30f; int i0 = 0;
#pragma unroll
        for (int e = 0; e < NEXP; e++) {
            float v = acc[e] + gb[e];
            acc[e] = v;
            if (v > v0) { v0 = v; i0 = e; }   // strict > : lowest index on tie
        }
        float v1 = -1e30f; int i1 = 0;
#pragma unroll
        for (int e = 0; e < NEXP; e++) {
            if (e != i0 && acc[e] > v1) { v1 = acc[e]; i1 = e; }
        }
        float e1 = expf(v1 - v0);
        float den = 1.f + e1;
        float g0 = 1.f / den;       // max gate score (>= 0.5)
        float g1 = e1 / den;
        unsigned sb = __float_as_uint(g0);  // g0 > 0 -> bit order == float order
        int s0 = 2 * t, s1 = 2 * t + 1;
        slot_expert[s0] = i0; slot_expert[s1] = i1;
        slot_gate[s0]   = g0; slot_gate[s1]   = g1;
        unsigned long long hi = ((unsigned long long)sb) << 32;
        slot_key[s0] = hi | (unsigned)(0xFFFFFFFFu - (unsigned)s0);
        slot_key[s1] = hi | (unsigned)(0xFFFFFFFFu - (unsigned)s1);
    }
}

// ------- bucket fill: LDS-aggregated histogram (64 blocks x 256 thr) -------
__global__ __launch_bounds__(256) void bucket_kernel(
        const int* __restrict__ slot_expert,
        const unsigned long long* __restrict__ slot_key,
        int* __restrict__ counts,
        unsigned long long* __restrict__ buckets) {
    __shared__ int lcnt[NEXP];
    __shared__ int lbase[NEXP];
    const int tid = threadIdx.x;
    const int s = blockIdx.x * 256 + tid;
    if (tid < NEXP) lcnt[tid] = 0;
    __syncthreads();
    const int e = slot_expert[s];
    const unsigned long long key = slot_key[s];
    const int lpos = atomicAdd(&lcnt[e], 1);        // LDS atomic: cheap
    __syncthreads();
    if (tid < NEXP) lbase[tid] = lcnt[tid] ? atomicAdd(&counts[tid], lcnt[tid]) : 0;
    __syncthreads();
    buckets[(size_t)e * NSLOT + lbase[e] + lpos] = key;
}

// ------- keep mask: one WAVE per slot + inline even-drop fallback write ----
// If an EVEN slot (token's top-1) is dropped, this wave immediately writes
// out[t] = g0 * x[t]  (each token has exactly one even slot -> sole writer;
// kept-even rows are written later by moe_gemm<0>, disjoint row sets).
__global__ __launch_bounds__(256) void keep_wave_kernel(
        const float* __restrict__ x,
        const int* __restrict__ slot_expert,
        const unsigned long long* __restrict__ slot_key,
        const int* __restrict__ counts,
        const unsigned long long* __restrict__ buckets,
        const float* __restrict__ slot_gate,
        int* __restrict__ slot_keep,
        float* __restrict__ out) {
    const int wv   = threadIdx.x >> 6;
    const int lane = threadIdx.x & 63;
    const int s    = blockIdx.x * 4 + wv;
    const int e    = slot_expert[s];
    const int c    = counts[e];
    int kp = 1;
    if (c > CAPE) {
        const unsigned long long k = slot_key[s];
        const unsigned long long* bk = buckets + (size_t)e * NSLOT;
        int rank = 0;
        for (int i = lane; i < c; i += 64) rank += (bk[i] > k) ? 1 : 0;
#pragma unroll
        for (int off = 32; off > 0; off >>= 1) rank += __shfl_down(rank, off, 64);
        kp = (__shfl(rank, 0, 64) < CAPE) ? 1 : 0;
    }
    if (lane == 0) slot_keep[s] = kp;
    if (!kp && !(s & 1)) {
        const int t = s >> 1;
        const float g = slot_gate[s];
        const floatx4* xr = (const floatx4*)(x + (size_t)t * DIM);
        floatx4* orow = (floatx4*)(out + (size_t)t * DIM);
#pragma unroll
        for (int i = 0; i < 4; i++) orow[lane + i * 64] = xr[lane + i * 64] * g;
    }
}

// ---- compact: parity-split elists + odd-drop list (64 blocks x 256 thr) ---
__global__ __launch_bounds__(256) void compact_kernel(
        const int* __restrict__ slot_expert,
        const int* __restrict__ slot_keep,
        int* __restrict__ ecntP,       // [2][NEXP]
        int* __restrict__ ndrop,       // [1] (odd drops only)
        int* __restrict__ elist0,      // kept even slots, [NEXP][CAPE]
        int* __restrict__ elist1,      // kept odd  slots, [NEXP][CAPE]
        int* __restrict__ droplist) {  // dropped odd slots
    __shared__ int lcnt[2 * NEXP];
    __shared__ int lbase[2 * NEXP];
    __shared__ int ldc, ldbase;
    const int tid = threadIdx.x;
    const int s = blockIdx.x * 256 + tid;
    if (tid < 2 * NEXP) lcnt[tid] = 0;
    if (tid == 2 * NEXP) ldc = 0;
    __syncthreads();
    const int e  = slot_expert[s];
    const int p  = s & 1;
    const int kp = slot_keep[s];
    const int idx = p * NEXP + e;
    int lpos = 0, dpos = 0;
    if (kp) lpos = atomicAdd(&lcnt[idx], 1);
    else if (p) dpos = atomicAdd(&ldc, 1);
    __syncthreads();
    if (tid < 2 * NEXP) lbase[tid] = lcnt[tid] ? atomicAdd(&ecntP[tid], lcnt[tid]) : 0;
    if (tid == 2 * NEXP) ldbase = ldc ? atomicAdd(ndrop, ldc) : 0;
    __syncthreads();
    if (kp) {
        int* el = p ? elist1 : elist0;
        el[e * CAPE + lbase[idx] + lpos] = s;
    } else if (p) {
        droplist[ldbase + dpos] = s;
    }
}

// ---------------- fp32 -> bf16 conversion (weights) ------------------------
__global__ void cvt_kernel(const float* __restrict__ src,
                           unsigned short* __restrict__ dst, int n4) {
    int i = blockIdx.x * blockDim.x + threadIdx.x;
    if (i >= n4) return;
    floatx4 v = ((const floatx4*)src)[i];
    ushort4v o;
    o[0] = f2bf(v[0]); o[1] = f2bf(v[1]); o[2] = f2bf(v[2]); o[3] = f2bf(v[3]);
    ((ushort4v*)dst)[i] = o;
}

// ---- dropped-odd fallback: out[t] += g1 * x[t] (after pass A wrote out) ---
__global__ __launch_bounds__(256) void drop_add_kernel(
        const float* __restrict__ x,
        const float* __restrict__ slot_gate,
        const int* __restrict__ droplist,
        const int* __restrict__ ndrop,
        float* __restrict__ out) {
    const int wv   = blockIdx.x * 4 + (threadIdx.x >> 6);
    const int lane = threadIdx.x & 63;
    const int nw   = gridDim.x * 4;
    const int nd   = *ndrop;
    for (int i = wv; i < nd; i += nw) {
        const int s = droplist[i];
        const int t = s >> 1;
        const float g = slot_gate[s];
        const floatx4* xr = (const floatx4*)(x + (size_t)t * DIM);
        floatx4* orow = (floatx4*)(out + (size_t)t * DIM);
#pragma unroll
        for (int j = 0; j < 4; j++) orow[lane + j * 64] += xr[lane + j * 64] * g;
    }
}

// --------- grouped expert GEMM: 256x128 tile, BK=32, parity passes ---------
// Core loop identical to round 2 (proven): double-buffered 48 KB LDS,
// global_load_lds staging with inverse-swizzled source, counted vmcnt(3),
// 2 raw barriers/tile, setprio around MFMA, 2 blocks/CU.
//
// PASS=0: kept EVEN slots (token top-1) -> plain store out[t] = g*y  (sole
//         writer per token row; dropped-even rows were written in keep_wave).
// PASS=1: kept ODD slots (token top-2)  -> out[t] += g*y (plain load-add-
//         store; exactly one odd slot per token -> no races).
// This removes the 64 MB fp32 ys round-trip + the combine kernel entirely.
template <int PASS>
__global__ __launch_bounds__(512, 4)
void moe_gemm(const unsigned short* __restrict__ Xb,
              const unsigned short* __restrict__ Wb,
              const float* __restrict__ eb,
              const int* __restrict__ elist,
              const int* __restrict__ ecnt,
              const float* __restrict__ slot_gate,
              float* __restrict__ out) {
    __shared__ unsigned short As[2][256 * 32];   // 16 KB x2
    __shared__ unsigned short Bs[2][128 * 32];   //  8 KB x2

    const int e  = blockIdx.z;
    const int ne = ecnt[e];
    const int m0 = blockIdx.y * 256;
    if (m0 >= ne) return;
    const int n0   = blockIdx.x * 128;
    const int tid  = threadIdx.x;
    const int wv   = tid >> 6;
    const int lane = tid & 63;
    const int q    = lane >> 4;
    const int l15  = lane & 15;
    const int wm   = (wv >> 1) * 64;   // wave M offset (4 M-waves)
    const int wn   = (wv & 1) * 64;    // wave N offset (2 N-waves)

    // --- staging source pointers (K-invariant); see round-2 comments ---
    const int srow = wv * 16 + (lane >> 2);           // 0..127
    const int jsrc = (lane & 3) ^ ((lane >> 3) & 3);
    const unsigned short* gA0;
    const unsigned short* gA1;
    {
        int m = m0 + srow;
        int slot = elist[e * CAPE + (m < ne ? m : 0)];
        gA0 = Xb + (size_t)(slot >> 1) * DIM + jsrc * 8;
        m = m0 + 128 + srow;
        slot = elist[e * CAPE + (m < ne ? m : 0)];
        gA1 = Xb + (size_t)(slot >> 1) * DIM + jsrc * 8;
    }
    const unsigned short* gB0 =
        Wb + (size_t)e * DIM * DIM + (size_t)(n0 + srow) * DIM + jsrc * 8;

#define STAGE(b, k0) do { \
    GLOAD_LDS16(gA0 + (k0), &As[b][(wv * 16) * 32]); \
    GLOAD_LDS16(gA1 + (k0), &As[b][(128 + wv * 16) * 32]); \
    GLOAD_LDS16(gB0 + (k0), &Bs[b][(wv * 16) * 32]); } while (0)

    // --- prologue: tiles 0,1 in flight ---
    STAGE(0, 0);
    STAGE(1, 32);

    // read-side offsets (shorts): row*32 + pos*8, pos = q ^ ((l15>>1)&3)
    const int swz  = (q ^ ((l15 >> 1) & 3)) * 8;
    const int aoff = (wm + l15) * 32 + swz;
    const int boff = (wn + l15) * 32 + swz;

    floatx4 acc[4][4] = {};
    short8 a[4], b[4];

    for (int t = 0; t < 32; t++) {
        const int cur = t & 1;
        if (t == 31) { asm volatile("s_waitcnt vmcnt(0)" ::: "memory"); }
        else         { asm volatile("s_waitcnt vmcnt(3)" ::: "memory"); }
        __builtin_amdgcn_sched_barrier(0);
        RAW_BARRIER();                       // tile-t data visible to all

        const unsigned short* A_ = &As[cur][0];
        const unsigned short* B_ = &Bs[cur][0];
#pragma unroll
        for (int fi = 0; fi < 4; fi++) a[fi] = *(const short8*)(A_ + aoff + fi * 512);
#pragma unroll
        for (int fj = 0; fj < 4; fj++) b[fj] = *(const short8*)(B_ + boff + fj * 512);

        __builtin_amdgcn_s_setprio(1);
#pragma unroll
        for (int fi = 0; fi < 4; fi++)
#pragma unroll
            for (int fj = 0; fj < 4; fj++)
                acc[fi][fj] = __builtin_amdgcn_mfma_f32_16x16x32_bf16(
                    a[fi], b[fj], acc[fi][fj], 0, 0, 0);
        __builtin_amdgcn_s_setprio(0);
        RAW_BARRIER();                       // all reads of buf[cur] complete

        if (t + 2 < 32) STAGE(cur, (t + 2) * 32);   // overwrite buf[cur]
    }
#undef STAGE

    // --- epilogue: C/D 16x16 layout col=lane&15, row=q*4+r ---
    float ebv[4];
#pragma unroll
    for (int fj = 0; fj < 4; fj++)
        ebv[fj] = eb[e * DIM + n0 + wn + fj * 16 + l15];
#pragma unroll
    for (int fi = 0; fi < 4; fi++) {
        const int mrow = m0 + wm + fi * 16 + q * 4;
#pragma unroll
        for (int r = 0; r < 4; r++) {
            int m = mrow + r;
            if (m >= ne) continue;
            int slot = elist[e * CAPE + m];
            int tok  = slot >> 1;
            float g  = slot_gate[slot];
            float* orow = out + (size_t)tok * DIM + n0 + wn;
#pragma unroll
            for (int fj = 0; fj < 4; fj++) {
                float v = g * (acc[fi][fj][r] + ebv[fj]);
                if (PASS == 0) orow[fj * 16 + l15] = v;
                else           orow[fj * 16 + l15] += v;
            }
        }
    }
}

extern "C" void kernel_launch(void* const* d_in, const int* in_sizes, int n_in,
                              void* d_out, int out_size, void* d_ws, size_t ws_size,
                              hipStream_t stream) {
    const float* x  = (const float*)d_in[0];   // [N, D]
    const float* gw = (const float*)d_in[1];   // [D, E]
    const float* gb = (const float*)d_in[2];   // [E]
    const float* ew = (const float*)d_in[3];   // [E, D, D]
    const float* eb = (const float*)d_in[4];   // [E, D]
    float* out = (float*)d_out;                // [N, D]

    char* ws = (char*)d_ws;
    // ---- workspace layout (bytes) ----
    int* counts      = (int*)(ws + 0);                   //    64 B
    int* ecntP       = (int*)(ws + 64);                  //   128 B [2][16]
    int* ndrop       = (int*)(ws + 192);                 //     4 B
    int* slot_expert = (int*)(ws + 256);                 //  64 KB
    int* slot_keep   = (int*)(ws + 65792);               //  64 KB
    float* slot_gate = (float*)(ws + 131328);            //  64 KB
    unsigned long long* slot_key = (unsigned long long*)(ws + 196864);  // 128 KB
    unsigned long long* buckets  = (unsigned long long*)(ws + 327936);  //   2 MB
    int* droplist    = (int*)(ws + 327936);              //  alias: buckets dead
                                                         //  after keep_wave
    int* elist0      = (int*)(ws + 2425088);             //  64 KB
    float* gwT       = (float*)(ws + 2490624);           //  64 KB
    unsigned short* Xb = (unsigned short*)(ws + 2556160);   // 16 MB
    unsigned short* Wb = (unsigned short*)(ws + 19333376);  // 32 MB -> end 52887808
    int* elist1      = (int*)(ws + 52887808);            //  64 KB -> end 52953344

    hipMemsetAsync(ws, 0, 256, stream);  // zero counts + ecntP + ndrop

    gwt_kernel <<<64, 256, 0, stream>>>(gw, gwT);
    gate_kernel<<<N_TOK / 4, 256, 0, stream>>>(x, gwT, gb, slot_expert, slot_key,
                                               slot_gate, Xb);
    bucket_kernel<<<NSLOT / 256, 256, 0, stream>>>(slot_expert, slot_key, counts, buckets);
    keep_wave_kernel<<<NSLOT / 4, 256, 0, stream>>>(x, slot_expert, slot_key, counts,
                                                    buckets, slot_gate, slot_keep, out);
    compact_kernel<<<NSLOT / 256, 256, 0, stream>>>(slot_expert, slot_keep, ecntP, ndrop,
                                                    elist0, elist1, droplist);
    cvt_kernel<<<(NEXP * DIM * DIM / 4) / 256, 256, 0, stream>>>(ew, Wb, NEXP * DIM * DIM / 4);

    // pass A: kept-even slots, plain store (rows disjoint from keep_wave's)
    moe_gemm<0><<<dim3(8, 4, 16), 512, 0, stream>>>(Xb, Wb, eb, elist0, ecntP,
                                                    slot_gate, out);
    // dropped-odd fallback: out += g*x (reads rows written by pass A / keep_wave)
    drop_add_kernel<<<64, 256, 0, stream>>>(x, slot_gate, droplist, ndrop, out);
    // pass B: kept-odd slots, out += g*y (sole writer per token row)
    moe_gemm<1><<<dim3(8, 4, 16), 512, 0, stream>>>(Xb, Wb, eb, elist1, ecntP + NEXP,
                                                    slot_gate, out);
}

// Round 5
// 246.683 us; speedup vs baseline: 1.1082x; 1.1082x over previous
//
#include <hip/hip_runtime.h>
#include <hip/hip_bf16.h>
#include <math.h>

#define N_TOK 8192
#define DIM   1024
#define NEXP  16
#define TOPK  2
#define CAPE  1024
#define NSLOT (N_TOK*TOPK)

typedef __attribute__((ext_vector_type(8))) short     short8;
typedef __attribute__((ext_vector_type(4))) float     floatx4;
typedef __attribute__((ext_vector_type(4))) unsigned short ushort4v;

__device__ __forceinline__ unsigned short f2bf(float f) {
    unsigned u = __float_as_uint(f);
    u += 0x7FFFu + ((u >> 16) & 1u);   // round-to-nearest-even
    return (unsigned short)(u >> 16);
}

// async global->LDS, 16B per lane; LDS dest = wave-uniform base + lane*16
#define GLOAD_LDS16(g, l) __builtin_amdgcn_global_load_lds( \
    (const __attribute__((address_space(1))) unsigned int*)(g), \
    (__attribute__((address_space(3))) unsigned int*)(l), 16, 0, 0)

#define RAW_BARRIER() asm volatile("s_barrier" ::: "memory")

// ---------------- gw transpose: [D,E] -> [E,D] (64 KB, one-shot) -----------
__global__ void gwt_kernel(const float* __restrict__ gw, float* __restrict__ gwT) {
    int i = blockIdx.x * 256 + threadIdx.x;
    if (i >= DIM * NEXP) return;
    int d = i >> 4, e = i & 15;
    gwT[e * DIM + d] = gw[i];
}

// ------- gate: logits -> top2 -> softmax -> slot records; fused x->bf16 ----
__global__ __launch_bounds__(256) void gate_kernel(
        const float* __restrict__ x,
        const float* __restrict__ gwT,
        const float* __restrict__ gb,
        int* __restrict__ slot_expert,
        unsigned long long* __restrict__ slot_key,
        float* __restrict__ slot_gate,
        unsigned short* __restrict__ Xb) {
    const int t    = blockIdx.x * 4 + (threadIdx.x >> 6);
    const int lane = threadIdx.x & 63;

    const floatx4* xr = (const floatx4*)(x + (size_t)t * DIM);
    ushort4v* Xb4 = (ushort4v*)Xb + (size_t)t * 256;
    floatx4 xv[4];
#pragma unroll
    for (int i = 0; i < 4; i++) {
        xv[i] = xr[lane + i * 64];
        ushort4v o;
        o[0] = f2bf(xv[i][0]); o[1] = f2bf(xv[i][1]);
        o[2] = f2bf(xv[i][2]); o[3] = f2bf(xv[i][3]);
        Xb4[lane + i * 64] = o;
    }

    float acc[NEXP];
#pragma unroll
    for (int e = 0; e < NEXP; e++) {
        const floatx4* wr = (const floatx4*)(gwT + (size_t)e * DIM);
        float a = 0.f;
#pragma unroll
        for (int i = 0; i < 4; i++) {
            floatx4 w = wr[lane + i * 64];
            a += xv[i][0]*w[0] + xv[i][1]*w[1] + xv[i][2]*w[2] + xv[i][3]*w[3];
        }
        acc[e] = a;
    }
#pragma unroll
    for (int off = 32; off > 0; off >>= 1) {
#pragma unroll
        for (int e = 0; e < NEXP; e++) acc[e] += __shfl_down(acc[e], off, 64);
    }
    if (lane == 0) {
        float v0 = -1e30f; int i0 = 0;
#pragma unroll
        for (int e = 0; e < NEXP; e++) {
            float v = acc[e] + gb[e];
            acc[e] = v;
            if (v > v0) { v0 = v; i0 = e; }   // strict > : lowest index on tie
        }
        float v1 = -1e30f; int i1 = 0;
#pragma unroll
        for (int e = 0; e < NEXP; e++) {
            if (e != i0 && acc[e] > v1) { v1 = acc[e]; i1 = e; }
        }
        float e1 = expf(v1 - v0);
        float den = 1.f + e1;
        float g0 = 1.f / den;       // max gate score (>= 0.5)
        float g1 = e1 / den;
        unsigned sb = __float_as_uint(g0);  // g0 > 0 -> bit order == float order
        int s0 = 2 * t, s1 = 2 * t + 1;
        slot_expert[s0] = i0; slot_expert[s1] = i1;
        slot_gate[s0]   = g0; slot_gate[s1]   = g1;
        unsigned long long hi = ((unsigned long long)sb) << 32;
        slot_key[s0] = hi | (unsigned)(0xFFFFFFFFu - (unsigned)s0);
        slot_key[s1] = hi | (unsigned)(0xFFFFFFFFu - (unsigned)s1);
    }
}

// ------- bucket fill: LDS-aggregated histogram (64 blocks x 256 thr) -------
__global__ __launch_bounds__(256) void bucket_kernel(
        const int* __restrict__ slot_expert,
        const unsigned long long* __restrict__ slot_key,
        int* __restrict__ counts,
        unsigned long long* __restrict__ buckets) {
    __shared__ int lcnt[NEXP];
    __shared__ int lbase[NEXP];
    const int tid = threadIdx.x;
    const int s = blockIdx.x * 256 + tid;
    if (tid < NEXP) lcnt[tid] = 0;
    __syncthreads();
    const int e = slot_expert[s];
    const unsigned long long key = slot_key[s];
    const int lpos = atomicAdd(&lcnt[e], 1);        // LDS atomic: cheap
    __syncthreads();
    if (tid < NEXP) lbase[tid] = lcnt[tid] ? atomicAdd(&counts[tid], lcnt[tid]) : 0;
    __syncthreads();
    buckets[(size_t)e * NSLOT + lbase[e] + lpos] = key;
}

// ---------------- keep mask: one WAVE per slot, lane-parallel rank scan ----
__global__ __launch_bounds__(256) void keep_wave_kernel(
        const int* __restrict__ slot_expert,
        const unsigned long long* __restrict__ slot_key,
        const int* __restrict__ counts,
        const unsigned long long* __restrict__ buckets,
        int* __restrict__ slot_keep) {
    const int wv   = threadIdx.x >> 6;
    const int lane = threadIdx.x & 63;
    const int s    = blockIdx.x * 4 + wv;
    const int e    = slot_expert[s];
    const int c    = counts[e];
    int kp = 1;
    if (c > CAPE) {
        const unsigned long long k = slot_key[s];
        const unsigned long long* bk = buckets + (size_t)e * NSLOT;
        int rank = 0;
        for (int i = lane; i < c; i += 64) rank += (bk[i] > k) ? 1 : 0;
#pragma unroll
        for (int off = 32; off > 0; off >>= 1) rank += __shfl_down(rank, off, 64);
        kp = (__shfl(rank, 0, 64) < CAPE) ? 1 : 0;
    }
    if (lane == 0) slot_keep[s] = kp;
}

// ---- compact: elist (+slot_pos), LDS-aggregated (64 blocks x 256 thr) -----
__global__ __launch_bounds__(256) void compact_kernel(
        const int* __restrict__ slot_expert,
        const int* __restrict__ slot_keep,
        int* __restrict__ ecount,
        int* __restrict__ elist,
        int* __restrict__ slot_pos) {
    __shared__ int lcnt[NEXP];
    __shared__ int lbase[NEXP];
    const int tid = threadIdx.x;
    const int s = blockIdx.x * 256 + tid;
    if (tid < NEXP) lcnt[tid] = 0;
    __syncthreads();
    const int e  = slot_expert[s];
    const int kp = slot_keep[s];
    int lpos = 0;
    if (kp) lpos = atomicAdd(&lcnt[e], 1);
    __syncthreads();
    if (tid < NEXP) lbase[tid] = lcnt[tid] ? atomicAdd(&ecount[tid], lcnt[tid]) : 0;
    __syncthreads();
    if (kp) {
        int p = lbase[e] + lpos;
        elist[e * CAPE + p] = s;
        if (slot_pos) slot_pos[s] = e * CAPE + p;
    }
}

// ------- base (atomic-fallback path only): out[t] = (dropped g sum)*x[t] ---
__global__ void base_kernel(const float* __restrict__ x,
                            const int* __restrict__ keep,
                            const float* __restrict__ gate,
                            float* __restrict__ out) {
    int i = blockIdx.x * blockDim.x + threadIdx.x;   // float4 index
    int t = i >> 8;                                  // 256 float4 per row
    float c = 0.f;
    if (!keep[2 * t])     c += gate[2 * t];
    if (!keep[2 * t + 1]) c += gate[2 * t + 1];
    floatx4 v = ((const floatx4*)x)[i];
    ((floatx4*)out)[i] = v * c;
}

// --------- grouped expert GEMM: 256x128 tile, BK=32, 2 blocks/CU -----------
// Round-2 proven core (double-buffered 48 KB LDS, A via global_load_lds with
// inverse-swizzled source, counted vmcnt, 2 raw barriers/tile, setprio,
// 2 blocks/CU) + fused fp32->bf16 weight conversion in B staging. B is
// reg-staged: 2x global_load_dwordx4 (fp32 ew) -> f2bf (identical RNE bits
// as the old cvt kernel) -> one swizzled ds_write_b128. Saves the separate
// 96 MB cvt dispatch entirely.
//
// Per-wave vmcnt queue (audited; counters always drain, no deadlock):
//   tail(t): STAGE_A(t+2) [2 gload_lds] ; vmcnt(2) -> drains A(t+1)+B(t+1)
//            regs, leaves A(t+2) in flight ; cvt+ds_write B(t+1) into
//            buf[cur^1] (its previous occupant B(t-1) was read-complete at
//            bar2(t-1)) ; issue B(t+2) reg loads.
//   head(t): lgkmcnt(0) [own ds_write drained] ; s_barrier.
// vmcnt reaches 0 only at t>=30 drain.
template <bool STORE_YS>
__global__ __launch_bounds__(512, 4)
void moe_gemm(const unsigned short* __restrict__ Xb,
              const float* __restrict__ ew,
              const float* __restrict__ eb,
              const int* __restrict__ elist,
              const int* __restrict__ ecount,
              const float* __restrict__ slot_gate,
              float* __restrict__ ys,
              float* __restrict__ out) {
    __shared__ unsigned short As[2][256 * 32];   // 16 KB x2
    __shared__ unsigned short Bs[2][128 * 32];   //  8 KB x2

    const int e  = blockIdx.z;
    const int ne = ecount[e];
    const int m0 = blockIdx.y * 256;
    if (m0 >= ne) return;
    const int n0   = blockIdx.x * 128;
    const int tid  = threadIdx.x;
    const int wv   = tid >> 6;
    const int lane = tid & 63;
    const int q    = lane >> 4;
    const int l15  = lane & 15;
    const int wm   = (wv >> 1) * 64;   // wave M offset (4 M-waves)
    const int wn   = (wv & 1) * 64;    // wave N offset (2 N-waves)

    // --- A staging source (K-invariant, inverse-swizzled k-block) ---
    const int srow = wv * 16 + (lane >> 2);           // 0..127
    const int jsrc = (lane & 3) ^ ((lane >> 3) & 3);
    const unsigned short* gA0;
    const unsigned short* gA1;
    {
        int m = m0 + srow;
        int slot = elist[e * CAPE + (m < ne ? m : 0)];
        gA0 = Xb + (size_t)(slot >> 1) * DIM + jsrc * 8;
        m = m0 + 128 + srow;
        slot = elist[e * CAPE + (m < ne ? m : 0)];
        gA1 = Xb + (size_t)(slot >> 1) * DIM + jsrc * 8;
    }

    // --- B staging: thread covers row brow (0..127), k-quad bj; write is
    // directly swizzled (reg-staged, no global_load_lds constraint).
    const int brow = tid >> 2;
    const int bj   = tid & 3;
    const float* gBsrc =
        ew + (size_t)e * DIM * DIM + (size_t)(n0 + brow) * DIM + bj * 8;
    const int bdst = brow * 32 + (bj ^ ((brow >> 1) & 3)) * 8;  // shorts

#define STAGE_A(b, k0) do { \
    GLOAD_LDS16(gA0 + (k0), &As[b][(wv * 16) * 32]); \
    GLOAD_LDS16(gA1 + (k0), &As[b][(128 + wv * 16) * 32]); } while (0)

    floatx4 bv0, bv1;
#define LOADB(k0) do { bv0 = *(const floatx4*)(gBsrc + (k0)); \
                       bv1 = *(const floatx4*)(gBsrc + (k0) + 4); } while (0)
#define WRITEB(b) do { short8 t_; \
    t_[0] = (short)f2bf(bv0[0]); t_[1] = (short)f2bf(bv0[1]); \
    t_[2] = (short)f2bf(bv0[2]); t_[3] = (short)f2bf(bv0[3]); \
    t_[4] = (short)f2bf(bv1[0]); t_[5] = (short)f2bf(bv1[1]); \
    t_[6] = (short)f2bf(bv1[2]); t_[7] = (short)f2bf(bv1[3]); \
    *(short8*)&Bs[b][bdst] = t_; } while (0)

    // --- prologue ---
    LOADB(0);                                  // B(0) regs      [B0:2]
    STAGE_A(0, 0);                             // A(0)           [B0,A0:4]
    STAGE_A(1, 32);                            // A(1)           [6]
    asm volatile("s_waitcnt vmcnt(4)" ::: "memory");   // B0 regs landed
    __builtin_amdgcn_sched_barrier(0);
    WRITEB(0);                                 // B(0) -> buf0
    LOADB(32);                                 // B(1) regs  [A0,A1,B1:6]
    asm volatile("s_waitcnt vmcnt(4)" ::: "memory");   // A(0) in LDS
    __builtin_amdgcn_sched_barrier(0);

    // read-side offsets (shorts): row*32 + pos*8, pos = q ^ ((l15>>1)&3)
    const int swz  = (q ^ ((l15 >> 1) & 3)) * 8;
    const int aoff = (wm + l15) * 32 + swz;
    const int boff = (wn + l15) * 32 + swz;

    floatx4 acc[4][4] = {};
    short8 a[4], b[4];

    for (int t = 0; t < 32; t++) {
        const int cur = t & 1;
        // head: own ds_write drained, then block-wide barrier
        asm volatile("s_waitcnt lgkmcnt(0)" ::: "memory");
        __builtin_amdgcn_sched_barrier(0);
        RAW_BARRIER();

        const unsigned short* A_ = &As[cur][0];
        const unsigned short* B_ = &Bs[cur][0];
#pragma unroll
        for (int fi = 0; fi < 4; fi++) a[fi] = *(const short8*)(A_ + aoff + fi * 512);
#pragma unroll
        for (int fj = 0; fj < 4; fj++) b[fj] = *(const short8*)(B_ + boff + fj * 512);

        __builtin_amdgcn_s_setprio(1);
#pragma unroll
        for (int fi = 0; fi < 4; fi++)
#pragma unroll
            for (int fj = 0; fj < 4; fj++)
                acc[fi][fj] = __builtin_amdgcn_mfma_f32_16x16x32_bf16(
                    a[fi], b[fj], acc[fi][fj], 0, 0, 0);
        __builtin_amdgcn_s_setprio(0);
        RAW_BARRIER();                       // all reads of buf[cur] complete

        // tail
        if (t + 2 < 32) {
            STAGE_A(cur, (t + 2) * 32);      // A(t+2) -> buf[cur]
            asm volatile("s_waitcnt vmcnt(2)" ::: "memory");  // A(t+1)+B(t+1) done
        } else {
            asm volatile("s_waitcnt vmcnt(0)" ::: "memory");
        }
        __builtin_amdgcn_sched_barrier(0);
        if (t + 1 < 32) {
            WRITEB(cur ^ 1);                 // B(t+1) -> buf[cur^1]
            if (t + 2 < 32) LOADB((t + 2) * 32);   // B(t+2) regs
        }
    }
#undef STAGE_A
#undef LOADB
#undef WRITEB

    // --- epilogue: C/D 16x16 layout col=lane&15, row=q*4+r ---
    float ebv[4];
#pragma unroll
    for (int fj = 0; fj < 4; fj++)
        ebv[fj] = eb[e * DIM + n0 + wn + fj * 16 + l15];
#pragma unroll
    for (int fi = 0; fi < 4; fi++) {
        const int mrow = m0 + wm + fi * 16 + q * 4;
#pragma unroll
        for (int r = 0; r < 4; r++) {
            int m = mrow + r;
            if (m >= ne) continue;
            if (STORE_YS) {
                float* yrow = ys + ((size_t)e * CAPE + m) * DIM + n0 + wn;
#pragma unroll
                for (int fj = 0; fj < 4; fj++)
                    yrow[fj * 16 + l15] = acc[fi][fj][r] + ebv[fj];
            } else {
                int slot = elist[e * CAPE + m];
                int tok  = slot >> 1;
                float g  = slot_gate[slot];
                float* orow = out + (size_t)tok * DIM + n0 + wn;
#pragma unroll
                for (int fj = 0; fj < 4; fj++)
                    atomicAdd(orow + fj * 16 + l15, g * (acc[fi][fj][r] + ebv[fj]));
            }
        }
    }
}

// ---------------- combine: out = sum_k g_k * (keep ? ys[pos] : x) ----------
// x row is loaded only when at least one slot was dropped (block-uniform
// condition; ~95% of rows skip the 32 MB x re-read).
__global__ void combine_kernel(const float* __restrict__ x,
                               const float* __restrict__ ys,
                               const int* __restrict__ keep,
                               const int* __restrict__ pos,
                               const float* __restrict__ gate,
                               float* __restrict__ out) {
    int i = blockIdx.x * 256 + threadIdx.x;   // float4 index
    int t = i >> 8;
    int c = i & 255;
    int s0 = 2 * t, s1 = s0 + 1;
    int k0 = keep[s0], k1 = keep[s1];
    float g0 = gate[s0], g1 = gate[s1];
    floatx4 xv = {};
    if (!k0 || !k1) xv = ((const floatx4*)x)[i];   // block-uniform branch
    floatx4 r;
    if (k0) {
        floatx4 y0 = ((const floatx4*)ys)[((size_t)pos[s0] << 8) + c];
        r = y0 * g0;
    } else r = xv * g0;
    if (k1) {
        floatx4 y1 = ((const floatx4*)ys)[((size_t)pos[s1] << 8) + c];
        r += y1 * g1;
    } else r += xv * g1;
    ((floatx4*)out)[i] = r;
}

extern "C" void kernel_launch(void* const* d_in, const int* in_sizes, int n_in,
                              void* d_out, int out_size, void* d_ws, size_t ws_size,
                              hipStream_t stream) {
    const float* x  = (const float*)d_in[0];   // [N, D]
    const float* gw = (const float*)d_in[1];   // [D, E]
    const float* gb = (const float*)d_in[2];   // [E]
    const float* ew = (const float*)d_in[3];   // [E, D, D]
    const float* eb = (const float*)d_in[4];   // [E, D]
    float* out = (float*)d_out;                // [N, D]

    char* ws = (char*)d_ws;
    // ---- workspace layout (bytes); Wb region retired (cvt fused) ----
    int* counts      = (int*)(ws + 0);                   //    64 B
    int* ecount      = (int*)(ws + 64);                  //    64 B
    int* slot_expert = (int*)(ws + 256);                 //  64 KB
    int* slot_keep   = (int*)(ws + 65792);               //  64 KB
    float* slot_gate = (float*)(ws + 131328);            //  64 KB
    unsigned long long* slot_key = (unsigned long long*)(ws + 196864);  // 128 KB
    unsigned long long* buckets  = (unsigned long long*)(ws + 327936);  //   2 MB
    int* elist       = (int*)(ws + 2425088);             //  64 KB
    float* gwT       = (float*)(ws + 2490624);           //  64 KB
    unsigned short* Xb = (unsigned short*)(ws + 2556160);   // 16 MB
    int* slot_pos    = (int*)(ws + 52887808);            //  64 KB (ys path only)
    float* ys        = (float*)(ws + 52953344);          //  64 MB (ys path only)
    const size_t WS_NEED_YS = 52953344ull + (size_t)NEXP * CAPE * DIM * 4;  // ~114.5 MB

    const bool ys_path = (ws_size >= WS_NEED_YS);

    hipMemsetAsync(ws, 0, 256, stream);  // zero counts + ecount

    gwt_kernel <<<64, 256, 0, stream>>>(gw, gwT);
    gate_kernel<<<N_TOK / 4, 256, 0, stream>>>(x, gwT, gb, slot_expert, slot_key,
                                               slot_gate, Xb);
    bucket_kernel<<<NSLOT / 256, 256, 0, stream>>>(slot_expert, slot_key, counts, buckets);
    keep_wave_kernel<<<NSLOT / 4, 256, 0, stream>>>(slot_expert, slot_key, counts,
                                                    buckets, slot_keep);
    compact_kernel<<<NSLOT / 256, 256, 0, stream>>>(slot_expert, slot_keep, ecount, elist,
                                                    ys_path ? slot_pos : nullptr);

    if (ys_path) {
        moe_gemm<true><<<dim3(8, 4, 16), 512, 0, stream>>>(Xb, ew, eb, elist, ecount,
                                                           slot_gate, ys, out);
        combine_kernel<<<N_TOK, 256, 0, stream>>>(x, ys, slot_keep, slot_pos,
                                                  slot_gate, out);
    } else {
        base_kernel<<<(N_TOK * DIM / 4) / 256, 256, 0, stream>>>(x, slot_keep,
                                                                 slot_gate, out);
        moe_gemm<false><<<dim3(8, 4, 16), 512, 0, stream>>>(Xb, ew, eb, elist, ecount,
                                                            slot_gate, nullptr, out);
    }
}

// Round 6
// 245.971 us; speedup vs baseline: 1.1114x; 1.0029x over previous
//
#include <hip/hip_runtime.h>
#include <hip/hip_bf16.h>
#include <math.h>

#define N_TOK 8192
#define DIM   1024
#define NEXP  16
#define TOPK  2
#define CAPE  1024
#define NSLOT (N_TOK*TOPK)

typedef __attribute__((ext_vector_type(8))) short     short8;
typedef __attribute__((ext_vector_type(4))) float     floatx4;
typedef __attribute__((ext_vector_type(4))) unsigned short ushort4v;

__device__ __forceinline__ unsigned short f2bf(float f) {
    unsigned u = __float_as_uint(f);
    u += 0x7FFFu + ((u >> 16) & 1u);   // round-to-nearest-even
    return (unsigned short)(u >> 16);
}

// async global->LDS, 16B per lane; LDS dest = wave-uniform base + lane*16
#define GLOAD_LDS16(g, l) __builtin_amdgcn_global_load_lds( \
    (const __attribute__((address_space(1))) unsigned int*)(g), \
    (__attribute__((address_space(3))) unsigned int*)(l), 16, 0, 0)

#define RAW_BARRIER() asm volatile("s_barrier" ::: "memory")

// --- fused: weight fp32->bf16 cvt + gw transpose + counter zeroing --------
// grid 16384 x 256 covers NEXP*DIM*DIM/4 float4's exactly; first 64 blocks
// also do the [D,E]->[E,D] gw transpose; block 0 zeroes the 256-byte
// counter area (replaces hipMemsetAsync dispatch).
__global__ void cvt_gwt_zero_kernel(const float* __restrict__ ew,
                                    unsigned short* __restrict__ Wb,
                                    const float* __restrict__ gw,
                                    float* __restrict__ gwT,
                                    int* __restrict__ zws) {
    const int i = blockIdx.x * 256 + threadIdx.x;
    if (blockIdx.x == 0 && threadIdx.x < 64) zws[threadIdx.x] = 0;
    if (i < DIM * NEXP) {
        int d = i >> 4, e = i & 15;
        gwT[e * DIM + d] = gw[i];
    }
    floatx4 v = ((const floatx4*)ew)[i];
    ushort4v o;
    o[0] = f2bf(v[0]); o[1] = f2bf(v[1]); o[2] = f2bf(v[2]); o[3] = f2bf(v[3]);
    ((ushort4v*)Wb)[i] = o;
}

// ------- gate: logits -> top2 -> softmax -> slot records; fused x->bf16 ----
// Round-6: bucket histogram FUSED in (LDS-aggregated over the block's 8
// slots, one global atomicAdd per present expert). The bucket insertion
// index (dense, unique within expert) is stashed in slot_keep[s] for the
// under-capacity fast path of keep_compact.
__global__ __launch_bounds__(256) void gate_kernel(
        const float* __restrict__ x,
        const float* __restrict__ gwT,
        const float* __restrict__ gb,
        int* __restrict__ slot_expert,
        unsigned long long* __restrict__ slot_key,
        float* __restrict__ slot_gate,
        unsigned short* __restrict__ Xb,
        int* __restrict__ counts,
        unsigned long long* __restrict__ buckets,
        int* __restrict__ slot_bpos) {   // == slot_keep array (temp use)
    __shared__ int se[8];
    __shared__ unsigned long long sk[8];
    __shared__ int lcnt[NEXP], lbase[NEXP], lpo[8];
    const int tid  = threadIdx.x;
    const int wv   = tid >> 6;
    const int t    = blockIdx.x * 4 + wv;
    const int lane = tid & 63;
    if (tid < NEXP) lcnt[tid] = 0;

    const floatx4* xr = (const floatx4*)(x + (size_t)t * DIM);
    ushort4v* Xb4 = (ushort4v*)Xb + (size_t)t * 256;
    floatx4 xv[4];
#pragma unroll
    for (int i = 0; i < 4; i++) {
        xv[i] = xr[lane + i * 64];
        ushort4v o;
        o[0] = f2bf(xv[i][0]); o[1] = f2bf(xv[i][1]);
        o[2] = f2bf(xv[i][2]); o[3] = f2bf(xv[i][3]);
        Xb4[lane + i * 64] = o;
    }

    float acc[NEXP];
#pragma unroll
    for (int e = 0; e < NEXP; e++) {
        const floatx4* wr = (const floatx4*)(gwT + (size_t)e * DIM);
        float a = 0.f;
#pragma unroll
        for (int i = 0; i < 4; i++) {
            floatx4 w = wr[lane + i * 64];
            a += xv[i][0]*w[0] + xv[i][1]*w[1] + xv[i][2]*w[2] + xv[i][3]*w[3];
        }
        acc[e] = a;
    }
#pragma unroll
    for (int off = 32; off > 0; off >>= 1) {
#pragma unroll
        for (int e = 0; e < NEXP; e++) acc[e] += __shfl_down(acc[e], off, 64);
    }
    if (lane == 0) {
        float v0 = -1e30f; int i0 = 0;
#pragma unroll
        for (int e = 0; e < NEXP; e++) {
            float v = acc[e] + gb[e];
            acc[e] = v;
            if (v > v0) { v0 = v; i0 = e; }   // strict > : lowest index on tie
        }
        float v1 = -1e30f; int i1 = 0;
#pragma unroll
        for (int e = 0; e < NEXP; e++) {
            if (e != i0 && acc[e] > v1) { v1 = acc[e]; i1 = e; }
        }
        float e1 = expf(v1 - v0);
        float den = 1.f + e1;
        float g0 = 1.f / den;       // max gate score (>= 0.5)
        float g1 = e1 / den;
        unsigned sb = __float_as_uint(g0);  // g0 > 0 -> bit order == float order
        int s0 = 2 * t, s1 = 2 * t + 1;
        slot_expert[s0] = i0; slot_expert[s1] = i1;
        slot_gate[s0]   = g0; slot_gate[s1]   = g1;
        unsigned long long hi = ((unsigned long long)sb) << 32;
        unsigned long long k0 = hi | (unsigned)(0xFFFFFFFFu - (unsigned)s0);
        unsigned long long k1 = hi | (unsigned)(0xFFFFFFFFu - (unsigned)s1);
        slot_key[s0] = k0; slot_key[s1] = k1;
        se[2 * wv] = i0; se[2 * wv + 1] = i1;
        sk[2 * wv] = k0; sk[2 * wv + 1] = k1;
    }
    __syncthreads();
    if (tid < 8) lpo[tid] = atomicAdd(&lcnt[se[tid]], 1);
    __syncthreads();
    if (tid < NEXP) lbase[tid] = lcnt[tid] ? atomicAdd(&counts[tid], lcnt[tid]) : 0;
    __syncthreads();
    if (tid < 8) {
        int e = se[tid];
        int p = lbase[e] + lpo[tid];
        buckets[(size_t)e * NSLOT + p] = sk[tid];
        slot_bpos[blockIdx.x * 8 + tid] = p;   // dense unique pos within expert
    }
}

// ---- keep+compact merged: one WAVE per slot, rank == elist position -------
// Keys are unique, so for an over-capacity expert the rank (count of larger
// keys) is a dense unique index in [0,c): kp = rank<CAPE, pos = rank.
// For an under-capacity expert every slot is kept and the gate-phase bucket
// insertion index (stashed in slot_keep[s]) is already dense+unique.
// -> elist/slot_pos written with NO atomics; ecount == min(counts,CAPE).
__global__ __launch_bounds__(256) void keep_compact_kernel(
        const int* __restrict__ slot_expert,
        const unsigned long long* __restrict__ slot_key,
        const int* __restrict__ counts,
        const unsigned long long* __restrict__ buckets,
        int* __restrict__ slot_keep,     // in: bucket pos; out: keep flag
        int* __restrict__ elist,
        int* __restrict__ slot_pos) {
    const int wv   = threadIdx.x >> 6;
    const int lane = threadIdx.x & 63;
    const int s    = blockIdx.x * 4 + wv;
    const int e    = slot_expert[s];
    const int c    = counts[e];
    int kp = 1, pos;
    if (c <= CAPE) {
        pos = slot_keep[s];              // bucket insertion index
    } else {
        const unsigned long long k = slot_key[s];
        const unsigned long long* bk = buckets + (size_t)e * NSLOT;
        int rank = 0;
        for (int i = lane; i < c; i += 64) rank += (bk[i] > k) ? 1 : 0;
#pragma unroll
        for (int off = 32; off > 0; off >>= 1) rank += __shfl_down(rank, off, 64);
        rank = __shfl(rank, 0, 64);
        kp  = (rank < CAPE) ? 1 : 0;
        pos = rank;
    }
    if (lane == 0) {
        slot_keep[s] = kp;
        if (kp) {
            int p = e * CAPE + pos;
            elist[p]    = s;
            slot_pos[s] = p;
        }
    }
}

// ------- base (atomic-fallback path only): out[t] = (dropped g sum)*x[t] ---
__global__ void base_kernel(const float* __restrict__ x,
                            const int* __restrict__ keep,
                            const float* __restrict__ gate,
                            float* __restrict__ out) {
    int i = blockIdx.x * blockDim.x + threadIdx.x;   // float4 index
    int t = i >> 8;                                  // 256 float4 per row
    float c = 0.f;
    if (!keep[2 * t])     c += gate[2 * t];
    if (!keep[2 * t + 1]) c += gate[2 * t + 1];
    floatx4 v = ((const floatx4*)x)[i];
    ((floatx4*)out)[i] = v * c;
}

// --------- grouped expert GEMM: 256x128 tile, BK=32, 2 blocks/CU -----------
// Round-2 proven core, verbatim: double-buffered 48 KB LDS, A+B via
// global_load_lds with inverse-swizzled source, counted vmcnt(3), 2 raw
// barriers/tile, setprio around MFMA, 2 blocks/CU. Only change: ne comes
// from min(counts[e], CAPE) (ecount retired with the compact kernel).
template <bool STORE_YS>
__global__ __launch_bounds__(512, 4)
void moe_gemm(const unsigned short* __restrict__ Xb,
              const unsigned short* __restrict__ Wb,
              const float* __restrict__ eb,
              const int* __restrict__ elist,
              const int* __restrict__ counts,
              const float* __restrict__ slot_gate,
              float* __restrict__ ys,
              float* __restrict__ out) {
    __shared__ unsigned short As[2][256 * 32];   // 16 KB x2
    __shared__ unsigned short Bs[2][128 * 32];   //  8 KB x2

    const int e  = blockIdx.z;
    int ne = counts[e]; if (ne > CAPE) ne = CAPE;
    const int m0 = blockIdx.y * 256;
    if (m0 >= ne) return;
    const int n0   = blockIdx.x * 128;
    const int tid  = threadIdx.x;
    const int wv   = tid >> 6;
    const int lane = tid & 63;
    const int q    = lane >> 4;
    const int l15  = lane & 15;
    const int wm   = (wv >> 1) * 64;   // wave M offset (4 M-waves)
    const int wn   = (wv & 1) * 64;    // wave N offset (2 N-waves)

    // --- staging source pointers (K-invariant) ---
    // wave wv stages rows [wv*16, wv*16+16) (+128 for A's 2nd instr); thread
    // lane L covers row srow = wv*16 + (L>>2), LDS k-pos L&3, so its global
    // k-block is j = (L&3) ^ ((row>>1)&3) = (L&3) ^ ((L>>3)&3).
    const int srow = wv * 16 + (lane >> 2);           // 0..127
    const int jsrc = (lane & 3) ^ ((lane >> 3) & 3);
    const unsigned short* gA0;
    const unsigned short* gA1;
    {
        int m = m0 + srow;
        int slot = elist[e * CAPE + (m < ne ? m : 0)];
        gA0 = Xb + (size_t)(slot >> 1) * DIM + jsrc * 8;
        m = m0 + 128 + srow;
        slot = elist[e * CAPE + (m < ne ? m : 0)];
        gA1 = Xb + (size_t)(slot >> 1) * DIM + jsrc * 8;
    }
    const unsigned short* gB0 =
        Wb + (size_t)e * DIM * DIM + (size_t)(n0 + srow) * DIM + jsrc * 8;

#define STAGE(b, k0) do { \
    GLOAD_LDS16(gA0 + (k0), &As[b][(wv * 16) * 32]); \
    GLOAD_LDS16(gA1 + (k0), &As[b][(128 + wv * 16) * 32]); \
    GLOAD_LDS16(gB0 + (k0), &Bs[b][(wv * 16) * 32]); } while (0)

    // --- prologue: tiles 0,1 in flight ---
    STAGE(0, 0);
    STAGE(1, 32);

    // read-side offsets (shorts): row*32 + pos*8, pos = q ^ ((l15>>1)&3)
    const int swz  = (q ^ ((l15 >> 1) & 3)) * 8;
    const int aoff = (wm + l15) * 32 + swz;
    const int boff = (wn + l15) * 32 + swz;

    floatx4 acc[4][4] = {};
    short8 a[4], b[4];

    for (int t = 0; t < 32; t++) {
        const int cur = t & 1;
        if (t == 31) { asm volatile("s_waitcnt vmcnt(0)" ::: "memory"); }
        else         { asm volatile("s_waitcnt vmcnt(3)" ::: "memory"); }
        __builtin_amdgcn_sched_barrier(0);
        RAW_BARRIER();                       // tile-t data visible to all

        const unsigned short* A_ = &As[cur][0];
        const unsigned short* B_ = &Bs[cur][0];
#pragma unroll
        for (int fi = 0; fi < 4; fi++) a[fi] = *(const short8*)(A_ + aoff + fi * 512);
#pragma unroll
        for (int fj = 0; fj < 4; fj++) b[fj] = *(const short8*)(B_ + boff + fj * 512);

        __builtin_amdgcn_s_setprio(1);
#pragma unroll
        for (int fi = 0; fi < 4; fi++)
#pragma unroll
            for (int fj = 0; fj < 4; fj++)
                acc[fi][fj] = __builtin_amdgcn_mfma_f32_16x16x32_bf16(
                    a[fi], b[fj], acc[fi][fj], 0, 0, 0);
        __builtin_amdgcn_s_setprio(0);
        RAW_BARRIER();                       // all reads of buf[cur] complete

        if (t + 2 < 32) STAGE(cur, (t + 2) * 32);   // overwrite buf[cur]
    }
#undef STAGE

    // --- epilogue: C/D 16x16 layout col=lane&15, row=q*4+r ---
    float ebv[4];
#pragma unroll
    for (int fj = 0; fj < 4; fj++)
        ebv[fj] = eb[e * DIM + n0 + wn + fj * 16 + l15];
#pragma unroll
    for (int fi = 0; fi < 4; fi++) {
        const int mrow = m0 + wm + fi * 16 + q * 4;
#pragma unroll
        for (int r = 0; r < 4; r++) {
            int m = mrow + r;
            if (m >= ne) continue;
            if (STORE_YS) {
                float* yrow = ys + ((size_t)e * CAPE + m) * DIM + n0 + wn;
#pragma unroll
                for (int fj = 0; fj < 4; fj++)
                    yrow[fj * 16 + l15] = acc[fi][fj][r] + ebv[fj];
            } else {
                int slot = elist[e * CAPE + m];
                int tok  = slot >> 1;
                float g  = slot_gate[slot];
                float* orow = out + (size_t)tok * DIM + n0 + wn;
#pragma unroll
                for (int fj = 0; fj < 4; fj++)
                    atomicAdd(orow + fj * 16 + l15, g * (acc[fi][fj][r] + ebv[fj]));
            }
        }
    }
}

// ---------------- combine: out = sum_k g_k * (keep ? ys[pos] : x) ----------
// x row is loaded only when at least one slot was dropped (block-uniform
// condition; ~95% of rows skip the 32 MB x re-read).
__global__ void combine_kernel(const float* __restrict__ x,
                               const float* __restrict__ ys,
                               const int* __restrict__ keep,
                               const int* __restrict__ pos,
                               const float* __restrict__ gate,
                               float* __restrict__ out) {
    int i = blockIdx.x * 256 + threadIdx.x;   // float4 index
    int t = i >> 8;
    int c = i & 255;
    int s0 = 2 * t, s1 = s0 + 1;
    int k0 = keep[s0], k1 = keep[s1];
    float g0 = gate[s0], g1 = gate[s1];
    floatx4 xv = {};
    if (!k0 || !k1) xv = ((const floatx4*)x)[i];   // block-uniform branch
    floatx4 r;
    if (k0) {
        floatx4 y0 = ((const floatx4*)ys)[((size_t)pos[s0] << 8) + c];
        r = y0 * g0;
    } else r = xv * g0;
    if (k1) {
        floatx4 y1 = ((const floatx4*)ys)[((size_t)pos[s1] << 8) + c];
        r += y1 * g1;
    } else r += xv * g1;
    ((floatx4*)out)[i] = r;
}

extern "C" void kernel_launch(void* const* d_in, const int* in_sizes, int n_in,
                              void* d_out, int out_size, void* d_ws, size_t ws_size,
                              hipStream_t stream) {
    const float* x  = (const float*)d_in[0];   // [N, D]
    const float* gw = (const float*)d_in[1];   // [D, E]
    const float* gb = (const float*)d_in[2];   // [E]
    const float* ew = (const float*)d_in[3];   // [E, D, D]
    const float* eb = (const float*)d_in[4];   // [E, D]
    float* out = (float*)d_out;                // [N, D]

    char* ws = (char*)d_ws;
    // ---- workspace layout (bytes); same offsets as round 2 ----
    int* counts      = (int*)(ws + 0);                   //    64 B
    int* slot_expert = (int*)(ws + 256);                 //  64 KB
    int* slot_keep   = (int*)(ws + 65792);               //  64 KB (temp: bpos)
    float* slot_gate = (float*)(ws + 131328);            //  64 KB
    unsigned long long* slot_key = (unsigned long long*)(ws + 196864);  // 128 KB
    unsigned long long* buckets  = (unsigned long long*)(ws + 327936);  //   2 MB
    int* elist       = (int*)(ws + 2425088);             //  64 KB
    float* gwT       = (float*)(ws + 2490624);           //  64 KB
    unsigned short* Xb = (unsigned short*)(ws + 2556160);   // 16 MB
    unsigned short* Wb = (unsigned short*)(ws + 19333376);  // 32 MB -> end 52887808
    int* slot_pos    = (int*)(ws + 52887808);            //  64 KB (ys path only)
    float* ys        = (float*)(ws + 52953344);          //  64 MB (ys path only)
    const size_t WS_NEED_YS = 52953344ull + (size_t)NEXP * CAPE * DIM * 4;  // ~114.5 MB

    const bool ys_path = (ws_size >= WS_NEED_YS);

    // 1) weight cvt + gw transpose + zero counters (fused, replaces 3 dispatches)
    cvt_gwt_zero_kernel<<<(NEXP * DIM * DIM / 4) / 256, 256, 0, stream>>>(
        ew, Wb, gw, gwT, (int*)ws);
    // 2) gate + fused bucket histogram (bpos stashed in slot_keep)
    gate_kernel<<<N_TOK / 4, 256, 0, stream>>>(x, gwT, gb, slot_expert, slot_key,
                                               slot_gate, Xb, counts, buckets,
                                               slot_keep);
    // 3) keep + compact merged (rank == position, no atomics)
    keep_compact_kernel<<<NSLOT / 4, 256, 0, stream>>>(slot_expert, slot_key, counts,
                                                       buckets, slot_keep, elist,
                                                       slot_pos);

    if (ys_path) {
        moe_gemm<true><<<dim3(8, 4, 16), 512, 0, stream>>>(Xb, Wb, eb, elist, counts,
                                                           slot_gate, ys, out);
        combine_kernel<<<N_TOK, 256, 0, stream>>>(x, ys, slot_keep, slot_pos,
                                                  slot_gate, out);
    } else {
        base_kernel<<<(N_TOK * DIM / 4) / 256, 256, 0, stream>>>(x, slot_keep,
                                                                 slot_gate, out);
        moe_gemm<false><<<dim3(8, 4, 16), 512, 0, stream>>>(Xb, Wb, eb, elist, counts,
                                                            slot_gate, nullptr, out);
    }
}